// Round 1
// baseline (2716.169 us; speedup 1.0000x reference)
//
#include <hip/hip_runtime.h>
#include <hip/hip_bf16.h>

#define B_ 4096
#define N_ 30
#define D_ 512
#define H_ 4
#define M_ (B_*N_)      // 122880 tokens
#define PE_ROWS 31

typedef unsigned short u16;

__device__ __forceinline__ float bf2f(u16 s) { return __uint_as_float(((unsigned)s) << 16); }
__device__ __forceinline__ u16 f2bf(float f) {
  __hip_bfloat16 h = __float2bfloat16(f);
  return *reinterpret_cast<u16*>(&h);
}

// block-wide sum over 512 threads (8 waves of 64)
__device__ __forceinline__ float bsum512(float v, float* red) {
  int lane = threadIdx.x & 63;
  int w = threadIdx.x >> 6;
  #pragma unroll
  for (int m = 32; m >= 1; m >>= 1) v += __shfl_xor(v, m);
  if (lane == 0) red[w] = v;
  __syncthreads();
  if (threadIdx.x < 64) {
    float t = (lane < 8) ? red[lane] : 0.0f;
    #pragma unroll
    for (int m = 4; m >= 1; m >>= 1) t += __shfl_xor(t, m);
    if (lane == 0) red[0] = t;
  }
  __syncthreads();
  float r = red[0];
  __syncthreads();
  return r;
}

// K1: per-batch prep. normalize -> LN1 -> +pos_emb, weighted pools (mp, mpx),
// cosine sim. Stores x1 (bf16), mp, mpx, cos.
__global__ __launch_bounds__(512) void k1_prep(
    const float* __restrict__ x, const int* __restrict__ order,
    const float* __restrict__ ndocs, const float* __restrict__ dw,
    const float* __restrict__ pe, const float* __restrict__ g1,
    const float* __restrict__ bln1,
    u16* __restrict__ x1bf, float* __restrict__ mp, float* __restrict__ mpx,
    float* __restrict__ cosb) {
  __shared__ float xpf[N_][D_];   // 60 KB: xp rows in f32 for pass 2
  __shared__ float xps[N_];
  __shared__ float red[8];
  int b = blockIdx.x;
  int d = threadIdx.x;
  float g = g1[d], bl = bln1[d];
  float accmp = 0.f, accmpx = 0.f;
  for (int n = 0; n < N_; ++n) {
    int tok = b*N_ + n;
    float xv = x[(size_t)tok*D_ + d];
    float ss = bsum512(xv*xv, red);
    float inv = 1.f / fmaxf(sqrtf(ss), 1e-8f);
    float xn = xv * inv;
    float mu = bsum512(xn, red) * (1.f/D_);
    float m2 = ss*inv*inv*(1.f/D_);           // mean(xn^2), exact
    float var = m2 - mu*mu;
    float x1v = g * ((xn - mu) / sqrtf(var + 1e-5f)) + bl;
    x1bf[(size_t)tok*D_ + d] = f2bf(x1v);
    int o = order[tok];
    float xpv = x1v + pe[o*D_ + d];
    xpf[n][d] = xpv;
    float wv = dw[tok];
    accmp  += wv*xpv;
    accmpx += wv*x1v;
    float sq = bsum512(xpv*xpv, red);
    if (d == 0) xps[n] = sq;
  }
  float nd = ndocs[b];
  float mpv = accmp / nd, mpxv = accmpx / nd;
  mp[(size_t)b*D_ + d] = mpv;
  mpx[(size_t)b*D_ + d] = mpxv;
  float mpn = sqrtf(bsum512(mpv*mpv, red));
  for (int n = 0; n < N_; ++n) {
    float dv = bsum512(mpv * xpf[n][d], red);
    if (d == 0) cosb[b*N_ + n] = dv / fmaxf(mpn * sqrtf(xps[n]), 1e-8f);
  }
}

// peW[p][j] = pos_emb[p] @ W_top   (31 x 512)
__global__ __launch_bounds__(512) void k_pew(
    const float* __restrict__ pe, const float* __restrict__ w1,
    float* __restrict__ peW) {
  int p = blockIdx.x, j = threadIdx.x;
  float acc = 0.f;
  for (int dd = 0; dd < D_; ++dd) acc += pe[p*D_ + dd] * w1[(size_t)dd*D_ + j];
  peW[p*D_ + j] = acc;
}

// mpW[b][j] = mp[b] @ W_mid + fc1_b1[j]   (8 batches per block)
__global__ __launch_bounds__(512) void k2_mpw(
    const float* __restrict__ mp, const float* __restrict__ w1,
    const float* __restrict__ b1, float* __restrict__ mpW) {
  __shared__ float mps[8][D_];
  int j = threadIdx.x;
  int b0 = blockIdx.x * 8;
  #pragma unroll
  for (int r = 0; r < 8; ++r) mps[r][j] = mp[(size_t)(b0+r)*D_ + j];
  __syncthreads();
  float bv = b1[j];
  float acc[8] = {bv,bv,bv,bv,bv,bv,bv,bv};
  for (int dd = 0; dd < D_; ++dd) {
    float wv = w1[(size_t)(D_+dd)*D_ + j];
    #pragma unroll
    for (int r = 0; r < 8; ++r) acc[r] += mps[r][dd] * wv;
  }
  #pragma unroll
  for (int r = 0; r < 8; ++r) mpW[(size_t)(b0+r)*D_ + j] = acc[r];
}

// K4: big GEMM  pre = x1 @ W_top (+ per-row extras), fused tanh and @fc1_w2.
// Tile 64 rows x 64 cols, K-step 32, 4x4 micro. Writes per-colblock partial Z.
__global__ __launch_bounds__(256) void k4_fc1(
    const u16* __restrict__ x1bf, const float* __restrict__ w1,
    const float* __restrict__ w2, const int* __restrict__ order,
    const float* __restrict__ cosb, const float* __restrict__ mpW,
    const float* __restrict__ peW, float* __restrict__ partial) {
  __shared__ __align__(16) float As[64][36];   // [row][k]
  __shared__ __align__(16) float Bs[64][36];   // [col][k]
  __shared__ float w2s[64][4];
  __shared__ float wls[64];
  int tid = threadIdx.x;
  int row0 = blockIdx.x * 64;
  int col0 = blockIdx.y * 64;
  if (tid < 64) {
    wls[tid] = w1[(size_t)1024*D_ + col0 + tid];
    #pragma unroll
    for (int h = 0; h < 4; ++h) w2s[tid][h] = w2[(col0+tid)*4 + h];
  }
  int rg = tid >> 4, cg = tid & 15;
  float acc[4][4] = {};
  for (int k0 = 0; k0 < D_; k0 += 32) {
    for (int s = tid; s < 512; s += 256) {        // A: 64x32 bf16 -> f32
      int r = s >> 3, kc = (s & 7) * 4;
      uint2 u = *reinterpret_cast<const uint2*>(&x1bf[(size_t)(row0+r)*D_ + k0 + kc]);
      As[r][kc+0] = bf2f((u16)(u.x & 0xffffu));
      As[r][kc+1] = bf2f((u16)(u.x >> 16));
      As[r][kc+2] = bf2f((u16)(u.y & 0xffffu));
      As[r][kc+3] = bf2f((u16)(u.y >> 16));
    }
    for (int s = tid; s < 2048; s += 256) {       // B^T: 64 cols x 32 k
      int c = s & 63, kk = s >> 6;
      Bs[c][kk] = w1[(size_t)(k0+kk)*D_ + col0 + c];
    }
    __syncthreads();
    #pragma unroll
    for (int kk = 0; kk < 32; kk += 4) {
      float4 a[4], bv[4];
      #pragma unroll
      for (int i = 0; i < 4; ++i) a[i] = *(const float4*)&As[rg + 16*i][kk];
      #pragma unroll
      for (int j = 0; j < 4; ++j) bv[j] = *(const float4*)&Bs[cg + 16*j][kk];
      #pragma unroll
      for (int i = 0; i < 4; ++i)
        #pragma unroll
        for (int j = 0; j < 4; ++j)
          acc[i][j] += a[i].x*bv[j].x + a[i].y*bv[j].y + a[i].z*bv[j].z + a[i].w*bv[j].w;
    }
    __syncthreads();
  }
  #pragma unroll
  for (int i = 0; i < 4; ++i) {
    int m = row0 + rg + 16*i;
    int bidx = m / N_;
    int o = order[m];
    float cs = cosb[m];
    float zl[4] = {0,0,0,0};
    #pragma unroll
    for (int j = 0; j < 4; ++j) {
      int cl = cg + 16*j;
      int jg = col0 + cl;
      float pre = acc[i][j] + mpW[(size_t)bidx*D_ + jg] + peW[o*D_ + jg] + cs * wls[cl];
      float t = tanhf(pre);
      #pragma unroll
      for (int h = 0; h < 4; ++h) zl[h] += t * w2s[cl][h];
    }
    #pragma unroll
    for (int msk = 1; msk <= 8; msk <<= 1)
      #pragma unroll
      for (int h = 0; h < 4; ++h) zl[h] += __shfl_xor(zl[h], msk);
    if (cg == 0) {
      #pragma unroll
      for (int h = 0; h < 4; ++h)
        partial[((size_t)blockIdx.y * M_ + m)*4 + h] = zl[h];
    }
  }
}

// K5: per-batch. Sum partials -> Z, mask, softmax over n per head, reshape-
// faithful attention pool over x1, +mpx tile, LN2 -> Hh2 [B,2048]
__global__ __launch_bounds__(512) void k5_attn(
    const float* __restrict__ partial, const float* __restrict__ b2,
    const unsigned char* __restrict__ amask, const u16* __restrict__ x1bf,
    const float* __restrict__ mpx, const float* __restrict__ g2,
    const float* __restrict__ bln2, float* __restrict__ Hh2) {
  __shared__ float abuf[N_*H_];   // [n][h] flat; reused z -> A
  __shared__ float red[8];
  int b = blockIdx.x;
  int tid = threadIdx.x;
  if (tid < N_*H_) {
    int n = tid >> 2, h = tid & 3;
    float z = b2[h];
    #pragma unroll
    for (int cb = 0; cb < 8; ++cb) z += partial[((size_t)cb*M_ + b*N_ + n)*4 + h];
    if (amask[b*N_ + n]) z = -INFINITY;
    abuf[n*4 + h] = z;
  }
  __syncthreads();
  if (tid < H_) {   // per-head softmax over n (each thread owns its column)
    int h = tid;
    float mx = -INFINITY;
    for (int n = 0; n < N_; ++n) mx = fmaxf(mx, abuf[n*4+h]);
    float s = 0.f;
    for (int n = 0; n < N_; ++n) s += expf(abuf[n*4+h] - mx);
    float inv = 1.f / s;
    for (int n = 0; n < N_; ++n) abuf[n*4+h] = expf(abuf[n*4+h] - mx) * inv;
  }
  __syncthreads();
  int d = tid;
  float hv[4] = {0,0,0,0};
  for (int j = 0; j < N_; ++j) {
    float xv = bf2f(x1bf[(size_t)(b*N_ + j)*D_ + d]);
    // A_h[i][j] = A.flat[i*30+j] on the [n][h]-contiguous buffer (reshape!)
    #pragma unroll
    for (int i = 0; i < 4; ++i) hv[i] += abuf[i*N_ + j] * xv;
  }
  float mpxv = mpx[(size_t)b*D_ + d];
  #pragma unroll
  for (int i = 0; i < 4; ++i) hv[i] += mpxv;
  float s1 = bsum512(hv[0]+hv[1]+hv[2]+hv[3], red);
  float s2 = bsum512(hv[0]*hv[0]+hv[1]*hv[1]+hv[2]*hv[2]+hv[3]*hv[3], red);
  float mu = s1 * (1.f/2048.f);
  float var = s2 * (1.f/2048.f) - mu*mu;
  float rs = 1.f / sqrtf(var + 1e-5f);
  #pragma unroll
  for (int i = 0; i < 4; ++i) {
    int idx = i*D_ + d;
    Hh2[(size_t)b*2048 + idx] = g2[idx] * ((hv[i]-mu)*rs) + bln2[idx];
  }
}

// K6: fc2 GEMM  [4096,2048] @ [2048,512] + bias -> pred0
__global__ __launch_bounds__(256) void k6_fc2(
    const float* __restrict__ Hh2, const float* __restrict__ fw,
    const float* __restrict__ fb, float* __restrict__ pred0) {
  __shared__ __align__(16) float As[64][36];
  __shared__ __align__(16) float Bs[64][36];
  int tid = threadIdx.x;
  int row0 = blockIdx.x * 64;
  int col0 = blockIdx.y * 64;
  int rg = tid >> 4, cg = tid & 15;
  float acc[4][4] = {};
  for (int k0 = 0; k0 < 2048; k0 += 32) {
    for (int s = tid; s < 2048; s += 256) {
      int r = s >> 5, kk = s & 31;
      As[r][kk] = Hh2[(size_t)(row0+r)*2048 + k0 + kk];
    }
    for (int s = tid; s < 2048; s += 256) {
      int c = s & 63, kk = s >> 6;
      Bs[c][kk] = fw[(size_t)(k0+kk)*D_ + col0 + c];
    }
    __syncthreads();
    #pragma unroll
    for (int kk = 0; kk < 32; kk += 4) {
      float4 a[4], bv[4];
      #pragma unroll
      for (int i = 0; i < 4; ++i) a[i] = *(const float4*)&As[rg + 16*i][kk];
      #pragma unroll
      for (int j = 0; j < 4; ++j) bv[j] = *(const float4*)&Bs[cg + 16*j][kk];
      #pragma unroll
      for (int i = 0; i < 4; ++i)
        #pragma unroll
        for (int j = 0; j < 4; ++j)
          acc[i][j] += a[i].x*bv[j].x + a[i].y*bv[j].y + a[i].z*bv[j].z + a[i].w*bv[j].w;
    }
    __syncthreads();
  }
  #pragma unroll
  for (int j = 0; j < 4; ++j) {
    int jg = col0 + cg + 16*j;
    float fbv = fb[jg];
    #pragma unroll
    for (int i = 0; i < 4; ++i) {
      int m = row0 + rg + 16*i;
      pred0[(size_t)m*D_ + jg] = acc[i][j] + fbv;
    }
  }
}

// K7: LN3, + head-mean of Hh2, LN4 -> out
__global__ __launch_bounds__(512) void k7_final(
    const float* __restrict__ pred0, const float* __restrict__ Hh2,
    const float* __restrict__ g3, const float* __restrict__ b3,
    const float* __restrict__ g4, const float* __restrict__ b4,
    float* __restrict__ out) {
  __shared__ float red[8];
  int b = blockIdx.x, d = threadIdx.x;
  float p = pred0[(size_t)b*D_ + d];
  float s1 = bsum512(p, red);
  float s2 = bsum512(p*p, red);
  float mu = s1*(1.f/D_);
  float var = s2*(1.f/D_) - mu*mu;
  float p3 = g3[d]*((p-mu)/sqrtf(var+1e-5f)) + b3[d];
  const float* hb = Hh2 + (size_t)b*2048;
  float hm = 0.25f*(hb[d] + hb[512+d] + hb[1024+d] + hb[1536+d]);
  float q = p3 + hm;
  s1 = bsum512(q, red);
  s2 = bsum512(q*q, red);
  mu = s1*(1.f/D_);
  var = s2*(1.f/D_) - mu*mu;
  out[(size_t)b*D_ + d] = g4[d]*((q-mu)/sqrtf(var+1e-5f)) + b4[d];
}

extern "C" void kernel_launch(void* const* d_in, const int* in_sizes, int n_in,
                              void* d_out, int out_size, void* d_ws, size_t ws_size,
                              hipStream_t stream) {
  const float* x      = (const float*)d_in[0];
  const unsigned char* amask = (const unsigned char*)d_in[1]; // bool, all-false
  const int*   order  = (const int*)d_in[2];
  const float* ndocs  = (const float*)d_in[3];
  const float* dw     = (const float*)d_in[4];
  // d_in[5] clusters_centroids: unused by reference
  const float* pe     = (const float*)d_in[6];
  const float* w1     = (const float*)d_in[7];
  const float* b1     = (const float*)d_in[8];
  const float* w2     = (const float*)d_in[9];
  const float* b2     = (const float*)d_in[10];
  const float* fw     = (const float*)d_in[11];
  const float* fb     = (const float*)d_in[12];
  const float* g1     = (const float*)d_in[13];
  const float* bln1   = (const float*)d_in[14];
  const float* g2     = (const float*)d_in[15];
  const float* bln2   = (const float*)d_in[16];
  const float* g3     = (const float*)d_in[17];
  const float* b3     = (const float*)d_in[18];
  const float* g4     = (const float*)d_in[19];
  const float* b4     = (const float*)d_in[20];
  float* out = (float*)d_out;

  char* ws = (char*)d_ws;
  size_t off = 0;
  u16*   x1bf   = (u16*)(ws + off);   off += (size_t)M_*D_*2;        // 125.8 MB
  float* mp     = (float*)(ws + off); off += (size_t)B_*D_*4;        // 8.4 MB
  float* mpx    = (float*)(ws + off); off += (size_t)B_*D_*4;
  float* mpW    = (float*)(ws + off); off += (size_t)B_*D_*4;
  float* peW    = (float*)(ws + off); off += (size_t)PE_ROWS*D_*4;
  float* cosb   = (float*)(ws + off); off += (size_t)M_*4;
  float* partial= (float*)(ws + off); off += (size_t)8*M_*4*4;       // 15.7 MB
  float* Hh2    = (float*)(ws + off); off += (size_t)B_*2048*4;      // 33.6 MB
  float* pred0  = (float*)(ws + off); off += (size_t)B_*D_*4;
  (void)ws_size; (void)in_sizes; (void)n_in; (void)out_size;

  k_pew<<<PE_ROWS, 512, 0, stream>>>(pe, w1, peW);
  k1_prep<<<B_, 512, 0, stream>>>(x, order, ndocs, dw, pe, g1, bln1,
                                  x1bf, mp, mpx, cosb);
  k2_mpw<<<B_/8, 512, 0, stream>>>(mp, w1, b1, mpW);
  k4_fc1<<<dim3(M_/64, 8), 256, 0, stream>>>(x1bf, w1, w2, order, cosb,
                                             mpW, peW, partial);
  k5_attn<<<B_, 512, 0, stream>>>(partial, b2, amask, x1bf, mpx, g2, bln2, Hh2);
  k6_fc2<<<dim3(B_/64, 8), 256, 0, stream>>>(Hh2, fw, fb, pred0);
  k7_final<<<B_, 512, 0, stream>>>(pred0, Hh2, g3, b3, g4, b4, out);
}

// Round 2
// 1096.526 us; speedup vs baseline: 2.4771x; 2.4771x over previous
//
#include <hip/hip_runtime.h>
#include <hip/hip_bf16.h>

#define B_ 4096
#define N_ 30
#define D_ 512
#define H_ 4
#define M_ (B_*N_)      // 122880 tokens
#define PE_ROWS 31

typedef unsigned short u16;
typedef __attribute__((ext_vector_type(8))) short bf16x8;
typedef __attribute__((ext_vector_type(4))) float f32x4;

__device__ __forceinline__ float bf2f(u16 s) { return __uint_as_float(((unsigned)s) << 16); }
__device__ __forceinline__ u16 f2bf(float f) {
  __hip_bfloat16 h = __float2bfloat16(f);
  return *reinterpret_cast<u16*>(&h);
}

// block-wide sum over 512 threads (8 waves of 64)
__device__ __forceinline__ float bsum512(float v, float* red) {
  int lane = threadIdx.x & 63;
  int w = threadIdx.x >> 6;
  #pragma unroll
  for (int m = 32; m >= 1; m >>= 1) v += __shfl_xor(v, m);
  if (lane == 0) red[w] = v;
  __syncthreads();
  if (threadIdx.x < 64) {
    float t = (lane < 8) ? red[lane] : 0.0f;
    #pragma unroll
    for (int m = 4; m >= 1; m >>= 1) t += __shfl_xor(t, m);
    if (lane == 0) red[0] = t;
  }
  __syncthreads();
  float r = red[0];
  __syncthreads();
  return r;
}

// K1: per-batch prep. normalize -> LN1 -> +pos_emb, weighted pools (mp, mpx),
// cosine sim. Stores x1 (bf16), mp, mpx, cos.
__global__ __launch_bounds__(512) void k1_prep(
    const float* __restrict__ x, const int* __restrict__ order,
    const float* __restrict__ ndocs, const float* __restrict__ dw,
    const float* __restrict__ pe, const float* __restrict__ g1,
    const float* __restrict__ bln1,
    u16* __restrict__ x1bf, float* __restrict__ mp, float* __restrict__ mpx,
    float* __restrict__ cosb) {
  __shared__ float xpf[N_][D_];   // 60 KB: xp rows in f32 for pass 2
  __shared__ float xps[N_];
  __shared__ float red[8];
  int b = blockIdx.x;
  int d = threadIdx.x;
  float g = g1[d], bl = bln1[d];
  float accmp = 0.f, accmpx = 0.f;
  for (int n = 0; n < N_; ++n) {
    int tok = b*N_ + n;
    float xv = x[(size_t)tok*D_ + d];
    float ss = bsum512(xv*xv, red);
    float inv = 1.f / fmaxf(sqrtf(ss), 1e-8f);
    float xn = xv * inv;
    float mu = bsum512(xn, red) * (1.f/D_);
    float m2 = ss*inv*inv*(1.f/D_);           // mean(xn^2), exact
    float var = m2 - mu*mu;
    float x1v = g * ((xn - mu) / sqrtf(var + 1e-5f)) + bl;
    x1bf[(size_t)tok*D_ + d] = f2bf(x1v);
    int o = order[tok];
    float xpv = x1v + pe[o*D_ + d];
    xpf[n][d] = xpv;
    float wv = dw[tok];
    accmp  += wv*xpv;
    accmpx += wv*x1v;
    float sq = bsum512(xpv*xpv, red);
    if (d == 0) xps[n] = sq;
  }
  float nd = ndocs[b];
  float mpv = accmp / nd, mpxv = accmpx / nd;
  mp[(size_t)b*D_ + d] = mpv;
  mpx[(size_t)b*D_ + d] = mpxv;
  float mpn = sqrtf(bsum512(mpv*mpv, red));
  for (int n = 0; n < N_; ++n) {
    float dv = bsum512(mpv * xpf[n][d], red);
    if (d == 0) cosb[b*N_ + n] = dv / fmaxf(mpn * sqrtf(xps[n]), 1e-8f);
  }
}

// peW[p][j] = pos_emb[p] @ W_top   (31 x 512)
__global__ __launch_bounds__(512) void k_pew(
    const float* __restrict__ pe, const float* __restrict__ w1,
    float* __restrict__ peW) {
  int p = blockIdx.x, j = threadIdx.x;
  float acc = 0.f;
  for (int dd = 0; dd < D_; ++dd) acc += pe[p*D_ + dd] * w1[(size_t)dd*D_ + j];
  peW[p*D_ + j] = acc;
}

// mpW[b][j] = mp[b] @ W_mid + fc1_b1[j]   (8 batches per block)
__global__ __launch_bounds__(512) void k2_mpw(
    const float* __restrict__ mp, const float* __restrict__ w1,
    const float* __restrict__ b1, float* __restrict__ mpW) {
  __shared__ float mps[8][D_];
  int j = threadIdx.x;
  int b0 = blockIdx.x * 8;
  #pragma unroll
  for (int r = 0; r < 8; ++r) mps[r][j] = mp[(size_t)(b0+r)*D_ + j];
  __syncthreads();
  float bv = b1[j];
  float acc[8] = {bv,bv,bv,bv,bv,bv,bv,bv};
  for (int dd = 0; dd < D_; ++dd) {
    float wv = w1[(size_t)(D_+dd)*D_ + j];
    #pragma unroll
    for (int r = 0; r < 8; ++r) acc[r] += mps[r][dd] * wv;
  }
  #pragma unroll
  for (int r = 0; r < 8; ++r) mpW[(size_t)(b0+r)*D_ + j] = acc[r];
}

// w1T_bf[j][k] = bf16(w1[k][j]) for k<512 (W_top, transposed for B-frag loads)
__global__ __launch_bounds__(512) void k_cvtw1(const float* __restrict__ w1,
                                              u16* __restrict__ w1T) {
  int j = blockIdx.x, k = threadIdx.x;
  w1T[(size_t)j*512 + k] = f2bf(w1[(size_t)k*512 + j]);
}

// fwT_bf[j][k] = bf16(fw[k][j]), k<2048
__global__ __launch_bounds__(512) void k_cvtfw(const float* __restrict__ fw,
                                              u16* __restrict__ fwT) {
  int j = blockIdx.x;
  for (int k = threadIdx.x; k < 2048; k += 512)
    fwT[(size_t)j*2048 + k] = f2bf(fw[(size_t)k*512 + j]);
}

// K4: MFMA bf16 GEMM  pre = x1 @ W_top (+ per-row extras), fused tanh and @w2.
// BM=128, BN=512 (full width), BK=32. 8 waves in 2(M)x4(N); each wave 64x128.
// Epilogue reduces tanh(pre)*w2 over all 512 cols in-block -> Z[m][4].
__global__ __launch_bounds__(512) void k4_fc1(
    const u16* __restrict__ x1bf, const u16* __restrict__ w1T,
    const float* __restrict__ w1, const float* __restrict__ w2,
    const int* __restrict__ order, const float* __restrict__ cosb,
    const float* __restrict__ mpW, const float* __restrict__ peW,
    float* __restrict__ Z) {
  __shared__ u16 As[128*40];     // [row][k], stride 40 bf16 (80B: 2-way = free)
  __shared__ u16 Bs[512*40];     // [col][k]
  __shared__ float w2s[512*4];
  __shared__ float wls[512];
  __shared__ float zred[4*128*4]; // [wn][row][h]
  int tid = threadIdx.x;
  int row0 = blockIdx.x * 128;
  for (int s = tid; s < 2048; s += 512) w2s[s] = w2[s];
  wls[tid] = w1[(size_t)1024*D_ + tid];
  int wid = tid >> 6, lane = tid & 63;
  int wm = wid >> 2, wn = wid & 3;
  int lr = lane & 15, lk = lane >> 4;
  int sra = tid >> 2, ska = (tid & 3) << 3;     // A staging coords
  f32x4 acc[4][8] = {};
  bf16x8 ra, rb[4];
  // prologue prefetch (tile 0)
  ra = *(const bf16x8*)&x1bf[(size_t)(row0 + sra)*D_ + ska];
  #pragma unroll
  for (int p = 0; p < 4; ++p) {
    int idx = p*512 + tid;
    int c = idx >> 2, kc = (idx & 3) << 3;
    rb[p] = *(const bf16x8*)&w1T[(size_t)c*D_ + kc];
  }
  for (int k0 = 0; k0 < D_; k0 += 32) {
    __syncthreads();
    *(bf16x8*)&As[sra*40 + ska] = ra;
    #pragma unroll
    for (int p = 0; p < 4; ++p) {
      int idx = p*512 + tid;
      int c = idx >> 2, kc = (idx & 3) << 3;
      *(bf16x8*)&Bs[c*40 + kc] = rb[p];
    }
    __syncthreads();
    if (k0 + 32 < D_) {       // prefetch next tile while MFMAs run
      ra = *(const bf16x8*)&x1bf[(size_t)(row0 + sra)*D_ + k0 + 32 + ska];
      #pragma unroll
      for (int p = 0; p < 4; ++p) {
        int idx = p*512 + tid;
        int c = idx >> 2, kc = (idx & 3) << 3;
        rb[p] = *(const bf16x8*)&w1T[(size_t)c*D_ + k0 + 32 + kc];
      }
    }
    bf16x8 a[4];
    #pragma unroll
    for (int mf = 0; mf < 4; ++mf)
      a[mf] = *(const bf16x8*)&As[(wm*64 + mf*16 + lr)*40 + lk*8];
    #pragma unroll
    for (int nf = 0; nf < 8; ++nf) {
      bf16x8 bfr = *(const bf16x8*)&Bs[(wn*128 + nf*16 + lr)*40 + lk*8];
      #pragma unroll
      for (int mf = 0; mf < 4; ++mf)
        acc[mf][nf] = __builtin_amdgcn_mfma_f32_16x16x32_bf16(a[mf], bfr, acc[mf][nf], 0, 0, 0);
    }
  }
  __syncthreads();
  // epilogue: pre -> tanh -> dot w2, reduce over cols
  #pragma unroll
  for (int mf = 0; mf < 4; ++mf) {
    #pragma unroll
    for (int r = 0; r < 4; ++r) {
      int rowt = wm*64 + mf*16 + lk*4 + r;
      int m = row0 + rowt;
      int bidx = m / N_;
      int o = order[m];
      float cs = cosb[m];
      float z0=0.f, z1=0.f, z2=0.f, z3=0.f;
      #pragma unroll
      for (int nf = 0; nf < 8; ++nf) {
        int jl = wn*128 + nf*16 + lr;
        float pre = acc[mf][nf][r] + mpW[(size_t)bidx*D_ + jl]
                  + peW[o*D_ + jl] + cs * wls[jl];
        float t = tanhf(pre);
        z0 += t * w2s[jl*4+0]; z1 += t * w2s[jl*4+1];
        z2 += t * w2s[jl*4+2]; z3 += t * w2s[jl*4+3];
      }
      #pragma unroll
      for (int msk = 1; msk <= 8; msk <<= 1) {
        z0 += __shfl_xor(z0, msk); z1 += __shfl_xor(z1, msk);
        z2 += __shfl_xor(z2, msk); z3 += __shfl_xor(z3, msk);
      }
      if (lr == 0)
        *(float4*)&zred[(wn*128 + rowt)*4] = make_float4(z0, z1, z2, z3);
    }
  }
  __syncthreads();
  if (tid < 128) {
    float4 s0 = *(float4*)&zred[(0*128 + tid)*4];
    float4 s1 = *(float4*)&zred[(1*128 + tid)*4];
    float4 s2 = *(float4*)&zred[(2*128 + tid)*4];
    float4 s3 = *(float4*)&zred[(3*128 + tid)*4];
    float4 s;
    s.x = s0.x+s1.x+s2.x+s3.x; s.y = s0.y+s1.y+s2.y+s3.y;
    s.z = s0.z+s1.z+s2.z+s3.z; s.w = s0.w+s1.w+s2.w+s3.w;
    *(float4*)&Z[(size_t)(row0 + tid)*4] = s;
  }
}

// K5: per-batch. Z -> mask/softmax, reshape-faithful attention pool over x1,
// +mpx tile, LN2 -> Hh2 [B,2048] (f32 + bf16 copy for fc2)
__global__ __launch_bounds__(512) void k5_attn(
    const float* __restrict__ Z, const float* __restrict__ b2,
    const unsigned char* __restrict__ amask, const u16* __restrict__ x1bf,
    const float* __restrict__ mpx, const float* __restrict__ g2,
    const float* __restrict__ bln2, float* __restrict__ Hh2,
    u16* __restrict__ Hh2bf) {
  __shared__ float abuf[N_*H_];   // [n][h] flat; reused z -> A
  __shared__ float red[8];
  int b = blockIdx.x;
  int tid = threadIdx.x;
  if (tid < N_*H_) {
    int n = tid >> 2, h = tid & 3;
    float z = b2[h] + Z[(size_t)(b*N_ + n)*4 + h];
    if (amask[b*N_ + n]) z = -INFINITY;
    abuf[n*4 + h] = z;
  }
  __syncthreads();
  if (tid < H_) {   // per-head softmax over n
    int h = tid;
    float mx = -INFINITY;
    for (int n = 0; n < N_; ++n) mx = fmaxf(mx, abuf[n*4+h]);
    float s = 0.f;
    for (int n = 0; n < N_; ++n) s += expf(abuf[n*4+h] - mx);
    float inv = 1.f / s;
    for (int n = 0; n < N_; ++n) abuf[n*4+h] = expf(abuf[n*4+h] - mx) * inv;
  }
  __syncthreads();
  int d = tid;
  float hv[4] = {0,0,0,0};
  for (int j = 0; j < N_; ++j) {
    float xv = bf2f(x1bf[(size_t)(b*N_ + j)*D_ + d]);
    // A_h[i][j] = A.flat[i*30+j] on the [n][h]-contiguous buffer (reshape!)
    #pragma unroll
    for (int i = 0; i < 4; ++i) hv[i] += abuf[i*N_ + j] * xv;
  }
  float mpxv = mpx[(size_t)b*D_ + d];
  #pragma unroll
  for (int i = 0; i < 4; ++i) hv[i] += mpxv;
  float s1 = bsum512(hv[0]+hv[1]+hv[2]+hv[3], red);
  float s2 = bsum512(hv[0]*hv[0]+hv[1]*hv[1]+hv[2]*hv[2]+hv[3]*hv[3], red);
  float mu = s1 * (1.f/2048.f);
  float var = s2 * (1.f/2048.f) - mu*mu;
  float rs = 1.f / sqrtf(var + 1e-5f);
  #pragma unroll
  for (int i = 0; i < 4; ++i) {
    int idx = i*D_ + d;
    float v = g2[idx] * ((hv[i]-mu)*rs) + bln2[idx];
    Hh2[(size_t)b*2048 + idx] = v;
    Hh2bf[(size_t)b*2048 + idx] = f2bf(v);
  }
}

// K6: MFMA bf16 fc2 GEMM  [4096,2048] @ [2048,512] + bias -> pred0
// BM=64, BN=128, BK=64; 4 waves 2x2; grid (64,4)=256 blocks.
__global__ __launch_bounds__(256) void k6_fc2(
    const u16* __restrict__ Hh2bf, const u16* __restrict__ fwT,
    const float* __restrict__ fb, float* __restrict__ pred0) {
  __shared__ u16 As[64*72];      // [row][k], stride 72 bf16
  __shared__ u16 Bs[128*72];     // [col][k]
  int tid = threadIdx.x;
  int row0 = blockIdx.x * 64, col0 = blockIdx.y * 128;
  int wid = tid >> 6, lane = tid & 63;
  int wm = wid >> 1, wn = wid & 1;
  int lr = lane & 15, lk = lane >> 4;
  f32x4 acc[2][4] = {};
  bf16x8 raa[2], rbb[4];
  #pragma unroll
  for (int p = 0; p < 2; ++p) {
    int idx = p*256 + tid;
    raa[p] = *(const bf16x8*)&Hh2bf[(size_t)(row0 + (idx>>3))*2048 + ((idx&7)<<3)];
  }
  #pragma unroll
  for (int p = 0; p < 4; ++p) {
    int idx = p*256 + tid;
    rbb[p] = *(const bf16x8*)&fwT[(size_t)(col0 + (idx>>3))*2048 + ((idx&7)<<3)];
  }
  for (int k0 = 0; k0 < 2048; k0 += 64) {
    __syncthreads();
    #pragma unroll
    for (int p = 0; p < 2; ++p) {
      int idx = p*256 + tid;
      *(bf16x8*)&As[(idx>>3)*72 + ((idx&7)<<3)] = raa[p];
    }
    #pragma unroll
    for (int p = 0; p < 4; ++p) {
      int idx = p*256 + tid;
      *(bf16x8*)&Bs[(idx>>3)*72 + ((idx&7)<<3)] = rbb[p];
    }
    __syncthreads();
    if (k0 + 64 < 2048) {
      #pragma unroll
      for (int p = 0; p < 2; ++p) {
        int idx = p*256 + tid;
        raa[p] = *(const bf16x8*)&Hh2bf[(size_t)(row0 + (idx>>3))*2048 + k0 + 64 + ((idx&7)<<3)];
      }
      #pragma unroll
      for (int p = 0; p < 4; ++p) {
        int idx = p*256 + tid;
        rbb[p] = *(const bf16x8*)&fwT[(size_t)(col0 + (idx>>3))*2048 + k0 + 64 + ((idx&7)<<3)];
      }
    }
    #pragma unroll
    for (int kk = 0; kk < 2; ++kk) {
      bf16x8 a[2];
      #pragma unroll
      for (int mf = 0; mf < 2; ++mf)
        a[mf] = *(const bf16x8*)&As[(wm*32 + mf*16 + lr)*72 + kk*32 + lk*8];
      #pragma unroll
      for (int nf = 0; nf < 4; ++nf) {
        bf16x8 bfr = *(const bf16x8*)&Bs[(wn*64 + nf*16 + lr)*72 + kk*32 + lk*8];
        #pragma unroll
        for (int mf = 0; mf < 2; ++mf)
          acc[mf][nf] = __builtin_amdgcn_mfma_f32_16x16x32_bf16(a[mf], bfr, acc[mf][nf], 0, 0, 0);
      }
    }
  }
  #pragma unroll
  for (int mf = 0; mf < 2; ++mf)
    #pragma unroll
    for (int nf = 0; nf < 4; ++nf)
      #pragma unroll
      for (int r = 0; r < 4; ++r) {
        int m = row0 + wm*32 + mf*16 + lk*4 + r;
        int j = col0 + wn*64 + nf*16 + lr;
        pred0[(size_t)m*D_ + j] = acc[mf][nf][r] + fb[j];
      }
}

// K7: LN3, + head-mean of Hh2, LN4 -> out
__global__ __launch_bounds__(512) void k7_final(
    const float* __restrict__ pred0, const float* __restrict__ Hh2,
    const float* __restrict__ g3, const float* __restrict__ b3,
    const float* __restrict__ g4, const float* __restrict__ b4,
    float* __restrict__ out) {
  __shared__ float red[8];
  int b = blockIdx.x, d = threadIdx.x;
  float p = pred0[(size_t)b*D_ + d];
  float s1 = bsum512(p, red);
  float s2 = bsum512(p*p, red);
  float mu = s1*(1.f/D_);
  float var = s2*(1.f/D_) - mu*mu;
  float p3 = g3[d]*((p-mu)/sqrtf(var+1e-5f)) + b3[d];
  const float* hb = Hh2 + (size_t)b*2048;
  float hm = 0.25f*(hb[d] + hb[512+d] + hb[1024+d] + hb[1536+d]);
  float q = p3 + hm;
  s1 = bsum512(q, red);
  s2 = bsum512(q*q, red);
  mu = s1*(1.f/D_);
  var = s2*(1.f/D_) - mu*mu;
  out[(size_t)b*D_ + d] = g4[d]*((q-mu)/sqrtf(var+1e-5f)) + b4[d];
}

extern "C" void kernel_launch(void* const* d_in, const int* in_sizes, int n_in,
                              void* d_out, int out_size, void* d_ws, size_t ws_size,
                              hipStream_t stream) {
  const float* x      = (const float*)d_in[0];
  const unsigned char* amask = (const unsigned char*)d_in[1];
  const int*   order  = (const int*)d_in[2];
  const float* ndocs  = (const float*)d_in[3];
  const float* dw     = (const float*)d_in[4];
  const float* pe     = (const float*)d_in[6];
  const float* w1     = (const float*)d_in[7];
  const float* b1     = (const float*)d_in[8];
  const float* w2     = (const float*)d_in[9];
  const float* b2     = (const float*)d_in[10];
  const float* fw     = (const float*)d_in[11];
  const float* fb     = (const float*)d_in[12];
  const float* g1     = (const float*)d_in[13];
  const float* bln1   = (const float*)d_in[14];
  const float* g2     = (const float*)d_in[15];
  const float* bln2   = (const float*)d_in[16];
  const float* g3     = (const float*)d_in[17];
  const float* b3     = (const float*)d_in[18];
  const float* g4     = (const float*)d_in[19];
  const float* b4     = (const float*)d_in[20];
  float* out = (float*)d_out;

  char* ws = (char*)d_ws;
  size_t off = 0;
  u16*   x1bf   = (u16*)(ws + off);   off += (size_t)M_*D_*2;        // 125.8 MB
  float* mp     = (float*)(ws + off); off += (size_t)B_*D_*4;        // 8.4 MB (dead after k2 -> pred0 aliases)
  float* pred0  = mp;
  float* mpx    = (float*)(ws + off); off += (size_t)B_*D_*4;
  float* mpW    = (float*)(ws + off); off += (size_t)B_*D_*4;
  float* peW    = (float*)(ws + off); off += (size_t)PE_ROWS*D_*4;
  float* cosb   = (float*)(ws + off); off += (size_t)M_*4;
  float* Z      = (float*)(ws + off); off += (size_t)M_*4*4;         // 2.0 MB
  float* Hh2    = (float*)(ws + off); off += (size_t)B_*2048*4;      // 33.6 MB
  u16*   Hh2bf  = (u16*)(ws + off);   off += (size_t)B_*2048*2;      // 16.8 MB
  u16*   w1T    = (u16*)(ws + off);   off += (size_t)D_*D_*2;        // 0.5 MB
  u16*   fwT    = (u16*)(ws + off);   off += (size_t)D_*2048*2;      // 2.1 MB
  (void)ws_size; (void)in_sizes; (void)n_in; (void)out_size;

  k_cvtw1<<<D_, 512, 0, stream>>>(w1, w1T);
  k_cvtfw<<<D_, 512, 0, stream>>>(fw, fwT);
  k_pew<<<PE_ROWS, 512, 0, stream>>>(pe, w1, peW);
  k1_prep<<<B_, 512, 0, stream>>>(x, order, ndocs, dw, pe, g1, bln1,
                                  x1bf, mp, mpx, cosb);
  k2_mpw<<<B_/8, 512, 0, stream>>>(mp, w1, b1, mpW);
  k4_fc1<<<M_/128, 512, 0, stream>>>(x1bf, w1T, w1, w2, order, cosb,
                                     mpW, peW, Z);
  k5_attn<<<B_, 512, 0, stream>>>(Z, b2, amask, x1bf, mpx, g2, bln2, Hh2, Hh2bf);
  k6_fc2<<<dim3(B_/64, 4), 256, 0, stream>>>(Hh2bf, fwT, fb, pred0);
  k7_final<<<B_, 512, 0, stream>>>(pred0, Hh2, g3, b3, g4, b4, out);
}

// Round 3
// 506.692 us; speedup vs baseline: 5.3606x; 2.1641x over previous
//
#include <hip/hip_runtime.h>
#include <hip/hip_bf16.h>

#define B_ 4096
#define N_ 30
#define D_ 512
#define H_ 4
#define M_ (B_*N_)      // 122880 tokens
#define PE_ROWS 31

typedef unsigned short u16;
typedef __attribute__((ext_vector_type(8))) short bf16x8;
typedef __attribute__((ext_vector_type(4))) float f32x4;

__device__ __forceinline__ float bf2f(u16 s) { return __uint_as_float(((unsigned)s) << 16); }
__device__ __forceinline__ u16 f2bf(float f) {
  __hip_bfloat16 h = __float2bfloat16(f);
  return *reinterpret_cast<u16*>(&h);
}

// full-wave (64-lane) sum
__device__ __forceinline__ float wsum(float v) {
  #pragma unroll
  for (int m = 32; m >= 1; m >>= 1) v += __shfl_xor(v, m);
  return v;
}

// block-wide sum over 512 threads (8 waves of 64)
__device__ __forceinline__ float bsum512(float v, float* red) {
  int lane = threadIdx.x & 63;
  int w = threadIdx.x >> 6;
  #pragma unroll
  for (int m = 32; m >= 1; m >>= 1) v += __shfl_xor(v, m);
  if (lane == 0) red[w] = v;
  __syncthreads();
  if (threadIdx.x < 64) {
    float t = (lane < 8) ? red[lane] : 0.0f;
    #pragma unroll
    for (int m = 4; m >= 1; m >>= 1) t += __shfl_xor(t, m);
    if (lane == 0) red[0] = t;
  }
  __syncthreads();
  float r = red[0];
  __syncthreads();
  return r;
}

// K1 v2: wave-per-token. Each of 8 waves owns tokens n = wid+8t (t<4); a
// token's 512-elem row lives as 8 floats/lane. All row reductions are
// intra-wave shfl_xor (no barriers). Single __syncthreads for the cross-wave
// mp/mpx pool reduce. xp rows stay in registers for the cosine phase.
__global__ __launch_bounds__(512) void k1_prep(
    const float* __restrict__ x, const int* __restrict__ order,
    const float* __restrict__ ndocs, const float* __restrict__ dw,
    const float* __restrict__ pe, const float* __restrict__ g1,
    const float* __restrict__ bln1,
    u16* __restrict__ x1bf, float* __restrict__ mp, float* __restrict__ mpx,
    float* __restrict__ cosb) {
  __shared__ float lds_mp[8*512];
  __shared__ float lds_mpx[8*512];
  __shared__ float xps[32];
  int b = blockIdx.x;
  int tid = threadIdx.x;
  int wid = tid >> 6, lane = tid & 63;
  int d0 = lane * 8;
  float g[8], bl[8];
  *(float4*)&g[0]  = *(const float4*)&g1[d0];
  *(float4*)&g[4]  = *(const float4*)&g1[d0+4];
  *(float4*)&bl[0] = *(const float4*)&bln1[d0];
  *(float4*)&bl[4] = *(const float4*)&bln1[d0+4];
  float xp_reg[4][8];
  float accmp[8] = {0,0,0,0,0,0,0,0}, accmpx[8] = {0,0,0,0,0,0,0,0};
  // Phase A: per-token normalize -> LN1 -> +pos_emb; wave-local reductions
  #pragma unroll
  for (int t = 0; t < 4; ++t) {
    int n = wid + 8*t;
    if (n < N_) {
      int tok = b*N_ + n;
      float v[8];
      *(float4*)&v[0] = *(const float4*)&x[(size_t)tok*D_ + d0];
      *(float4*)&v[4] = *(const float4*)&x[(size_t)tok*D_ + d0 + 4];
      float ss = 0.f;
      #pragma unroll
      for (int i = 0; i < 8; ++i) ss += v[i]*v[i];
      ss = wsum(ss);
      float inv = 1.f / fmaxf(sqrtf(ss), 1e-8f);
      float mu = 0.f;
      #pragma unroll
      for (int i = 0; i < 8; ++i) { v[i] *= inv; mu += v[i]; }
      mu = wsum(mu) * (1.f/D_);
      float m2 = ss*inv*inv*(1.f/D_);   // mean(xn^2), exact
      float rs = 1.f / sqrtf(m2 - mu*mu + 1e-5f);
      int o = order[tok];
      float p8[8];
      *(float4*)&p8[0] = *(const float4*)&pe[(size_t)o*D_ + d0];
      *(float4*)&p8[4] = *(const float4*)&pe[(size_t)o*D_ + d0 + 4];
      float wv = dw[tok];
      float sq = 0.f;
      bf16x8 xb;
      #pragma unroll
      for (int i = 0; i < 8; ++i) {
        float x1v = g[i]*((v[i]-mu)*rs) + bl[i];
        xb[i] = (short)f2bf(x1v);
        float xpv = x1v + p8[i];
        xp_reg[t][i] = xpv;
        accmp[i]  += wv*xpv;
        accmpx[i] += wv*x1v;
        sq += xpv*xpv;
      }
      *(bf16x8*)&x1bf[(size_t)tok*D_ + d0] = xb;
      sq = wsum(sq);
      if (lane == 0) xps[n] = sq;
    }
  }
  // Phase B: cross-wave pool reduce (the only barrier)
  #pragma unroll
  for (int i = 0; i < 8; i += 4) {
    *(float4*)&lds_mp[wid*512 + d0 + i]  = *(float4*)&accmp[i];
    *(float4*)&lds_mpx[wid*512 + d0 + i] = *(float4*)&accmpx[i];
  }
  __syncthreads();
  float invnd = 1.f / ndocs[b];
  float mpv[8] = {0,0,0,0,0,0,0,0}, mpxv[8] = {0,0,0,0,0,0,0,0};
  #pragma unroll
  for (int w = 0; w < 8; ++w) {
    #pragma unroll
    for (int i = 0; i < 8; i += 4) {
      float4 a = *(float4*)&lds_mp[w*512 + d0 + i];
      mpv[i+0] += a.x; mpv[i+1] += a.y; mpv[i+2] += a.z; mpv[i+3] += a.w;
      float4 c = *(float4*)&lds_mpx[w*512 + d0 + i];
      mpxv[i+0] += c.x; mpxv[i+1] += c.y; mpxv[i+2] += c.z; mpxv[i+3] += c.w;
    }
  }
  #pragma unroll
  for (int i = 0; i < 8; ++i) { mpv[i] *= invnd; mpxv[i] *= invnd; }
  if (wid == 0) {
    #pragma unroll
    for (int i = 0; i < 8; i += 4)
      *(float4*)&mp[(size_t)b*D_ + d0 + i] = *(float4*)&mpv[i];
  }
  if (wid == 1) {
    #pragma unroll
    for (int i = 0; i < 8; i += 4)
      *(float4*)&mpx[(size_t)b*D_ + d0 + i] = *(float4*)&mpxv[i];
  }
  float mn = 0.f;
  #pragma unroll
  for (int i = 0; i < 8; ++i) mn += mpv[i]*mpv[i];
  float mpn = sqrtf(wsum(mn));
  // Phase C: cosine per token (wave-local, xp in registers)
  #pragma unroll
  for (int t = 0; t < 4; ++t) {
    int n = wid + 8*t;
    if (n < N_) {
      float dot = 0.f;
      #pragma unroll
      for (int i = 0; i < 8; ++i) dot += mpv[i]*xp_reg[t][i];
      dot = wsum(dot);
      if (lane == 0)
        cosb[b*N_ + n] = dot / fmaxf(mpn * sqrtf(xps[n]), 1e-8f);
    }
  }
}

// peW[p][j] = pos_emb[p] @ W_top   (31 x 512)
__global__ __launch_bounds__(512) void k_pew(
    const float* __restrict__ pe, const float* __restrict__ w1,
    float* __restrict__ peW) {
  int p = blockIdx.x, j = threadIdx.x;
  float acc = 0.f;
  for (int dd = 0; dd < D_; ++dd) acc += pe[p*D_ + dd] * w1[(size_t)dd*D_ + j];
  peW[p*D_ + j] = acc;
}

// mpW[b][j] = mp[b] @ W_mid + fc1_b1[j]   (8 batches per block)
__global__ __launch_bounds__(512) void k2_mpw(
    const float* __restrict__ mp, const float* __restrict__ w1,
    const float* __restrict__ b1, float* __restrict__ mpW) {
  __shared__ float mps[8][D_];
  int j = threadIdx.x;
  int b0 = blockIdx.x * 8;
  #pragma unroll
  for (int r = 0; r < 8; ++r) mps[r][j] = mp[(size_t)(b0+r)*D_ + j];
  __syncthreads();
  float bv = b1[j];
  float acc[8] = {bv,bv,bv,bv,bv,bv,bv,bv};
  for (int dd = 0; dd < D_; ++dd) {
    float wv = w1[(size_t)(D_+dd)*D_ + j];
    #pragma unroll
    for (int r = 0; r < 8; ++r) acc[r] += mps[r][dd] * wv;
  }
  #pragma unroll
  for (int r = 0; r < 8; ++r) mpW[(size_t)(b0+r)*D_ + j] = acc[r];
}

// w1T_bf[j][k] = bf16(w1[k][j]) for k<512 (W_top, transposed for B-frag loads)
__global__ __launch_bounds__(512) void k_cvtw1(const float* __restrict__ w1,
                                              u16* __restrict__ w1T) {
  int j = blockIdx.x, k = threadIdx.x;
  w1T[(size_t)j*512 + k] = f2bf(w1[(size_t)k*512 + j]);
}

// fwT_bf[j][k] = bf16(fw[k][j]), k<2048
__global__ __launch_bounds__(512) void k_cvtfw(const float* __restrict__ fw,
                                              u16* __restrict__ fwT) {
  int j = blockIdx.x;
  for (int k = threadIdx.x; k < 2048; k += 512)
    fwT[(size_t)j*2048 + k] = f2bf(fw[(size_t)k*512 + j]);
}

// K4: MFMA bf16 GEMM  pre = x1 @ W_top (+ per-row extras), fused tanh and @w2.
// BM=128, BN=512 (full width), BK=32. 8 waves in 2(M)x4(N); each wave 64x128.
// Epilogue reduces tanh(pre)*w2 over all 512 cols in-block -> Z[m][4].
__global__ __launch_bounds__(512) void k4_fc1(
    const u16* __restrict__ x1bf, const u16* __restrict__ w1T,
    const float* __restrict__ w1, const float* __restrict__ w2,
    const int* __restrict__ order, const float* __restrict__ cosb,
    const float* __restrict__ mpW, const float* __restrict__ peW,
    float* __restrict__ Z) {
  __shared__ u16 As[128*40];     // [row][k], stride 40 bf16 (80B: 2-way = free)
  __shared__ u16 Bs[512*40];     // [col][k]
  __shared__ float w2s[512*4];
  __shared__ float wls[512];
  __shared__ float zred[4*128*4]; // [wn][row][h]
  int tid = threadIdx.x;
  int row0 = blockIdx.x * 128;
  for (int s = tid; s < 2048; s += 512) w2s[s] = w2[s];
  wls[tid] = w1[(size_t)1024*D_ + tid];
  int wid = tid >> 6, lane = tid & 63;
  int wm = wid >> 2, wn = wid & 3;
  int lr = lane & 15, lk = lane >> 4;
  int sra = tid >> 2, ska = (tid & 3) << 3;     // A staging coords
  f32x4 acc[4][8] = {};
  bf16x8 ra, rb[4];
  // prologue prefetch (tile 0)
  ra = *(const bf16x8*)&x1bf[(size_t)(row0 + sra)*D_ + ska];
  #pragma unroll
  for (int p = 0; p < 4; ++p) {
    int idx = p*512 + tid;
    int c = idx >> 2, kc = (idx & 3) << 3;
    rb[p] = *(const bf16x8*)&w1T[(size_t)c*D_ + kc];
  }
  for (int k0 = 0; k0 < D_; k0 += 32) {
    __syncthreads();
    *(bf16x8*)&As[sra*40 + ska] = ra;
    #pragma unroll
    for (int p = 0; p < 4; ++p) {
      int idx = p*512 + tid;
      int c = idx >> 2, kc = (idx & 3) << 3;
      *(bf16x8*)&Bs[c*40 + kc] = rb[p];
    }
    __syncthreads();
    if (k0 + 32 < D_) {       // prefetch next tile while MFMAs run
      ra = *(const bf16x8*)&x1bf[(size_t)(row0 + sra)*D_ + k0 + 32 + ska];
      #pragma unroll
      for (int p = 0; p < 4; ++p) {
        int idx = p*512 + tid;
        int c = idx >> 2, kc = (idx & 3) << 3;
        rb[p] = *(const bf16x8*)&w1T[(size_t)c*D_ + k0 + 32 + kc];
      }
    }
    bf16x8 a[4];
    #pragma unroll
    for (int mf = 0; mf < 4; ++mf)
      a[mf] = *(const bf16x8*)&As[(wm*64 + mf*16 + lr)*40 + lk*8];
    #pragma unroll
    for (int nf = 0; nf < 8; ++nf) {
      bf16x8 bfr = *(const bf16x8*)&Bs[(wn*128 + nf*16 + lr)*40 + lk*8];
      #pragma unroll
      for (int mf = 0; mf < 4; ++mf)
        acc[mf][nf] = __builtin_amdgcn_mfma_f32_16x16x32_bf16(a[mf], bfr, acc[mf][nf], 0, 0, 0);
    }
  }
  __syncthreads();
  // epilogue: pre -> tanh -> dot w2, reduce over cols
  #pragma unroll
  for (int mf = 0; mf < 4; ++mf) {
    #pragma unroll
    for (int r = 0; r < 4; ++r) {
      int rowt = wm*64 + mf*16 + lk*4 + r;
      int m = row0 + rowt;
      int bidx = m / N_;
      int o = order[m];
      float cs = cosb[m];
      float z0=0.f, z1=0.f, z2=0.f, z3=0.f;
      #pragma unroll
      for (int nf = 0; nf < 8; ++nf) {
        int jl = wn*128 + nf*16 + lr;
        float pre = acc[mf][nf][r] + mpW[(size_t)bidx*D_ + jl]
                  + peW[o*D_ + jl] + cs * wls[jl];
        float t = tanhf(pre);
        z0 += t * w2s[jl*4+0]; z1 += t * w2s[jl*4+1];
        z2 += t * w2s[jl*4+2]; z3 += t * w2s[jl*4+3];
      }
      #pragma unroll
      for (int msk = 1; msk <= 8; msk <<= 1) {
        z0 += __shfl_xor(z0, msk); z1 += __shfl_xor(z1, msk);
        z2 += __shfl_xor(z2, msk); z3 += __shfl_xor(z3, msk);
      }
      if (lr == 0)
        *(float4*)&zred[(wn*128 + rowt)*4] = make_float4(z0, z1, z2, z3);
    }
  }
  __syncthreads();
  if (tid < 128) {
    float4 s0 = *(float4*)&zred[(0*128 + tid)*4];
    float4 s1 = *(float4*)&zred[(1*128 + tid)*4];
    float4 s2 = *(float4*)&zred[(2*128 + tid)*4];
    float4 s3 = *(float4*)&zred[(3*128 + tid)*4];
    float4 s;
    s.x = s0.x+s1.x+s2.x+s3.x; s.y = s0.y+s1.y+s2.y+s3.y;
    s.z = s0.z+s1.z+s2.z+s3.z; s.w = s0.w+s1.w+s2.w+s3.w;
    *(float4*)&Z[(size_t)(row0 + tid)*4] = s;
  }
}

// K5: per-batch. Z -> mask/softmax, reshape-faithful attention pool over x1,
// +mpx tile, LN2 -> Hh2 [B,2048] (f32 + bf16 copy for fc2)
__global__ __launch_bounds__(512) void k5_attn(
    const float* __restrict__ Z, const float* __restrict__ b2,
    const unsigned char* __restrict__ amask, const u16* __restrict__ x1bf,
    const float* __restrict__ mpx, const float* __restrict__ g2,
    const float* __restrict__ bln2, float* __restrict__ Hh2,
    u16* __restrict__ Hh2bf) {
  __shared__ float abuf[N_*H_];   // [n][h] flat; reused z -> A
  __shared__ float red[8];
  int b = blockIdx.x;
  int tid = threadIdx.x;
  if (tid < N_*H_) {
    int n = tid >> 2, h = tid & 3;
    float z = b2[h] + Z[(size_t)(b*N_ + n)*4 + h];
    if (amask[b*N_ + n]) z = -INFINITY;
    abuf[n*4 + h] = z;
  }
  __syncthreads();
  if (tid < H_) {   // per-head softmax over n
    int h = tid;
    float mx = -INFINITY;
    for (int n = 0; n < N_; ++n) mx = fmaxf(mx, abuf[n*4+h]);
    float s = 0.f;
    for (int n = 0; n < N_; ++n) s += expf(abuf[n*4+h] - mx);
    float inv = 1.f / s;
    for (int n = 0; n < N_; ++n) abuf[n*4+h] = expf(abuf[n*4+h] - mx) * inv;
  }
  __syncthreads();
  int d = tid;
  float hv[4] = {0,0,0,0};
  for (int j = 0; j < N_; ++j) {
    float xv = bf2f(x1bf[(size_t)(b*N_ + j)*D_ + d]);
    // A_h[i][j] = A.flat[i*30+j] on the [n][h]-contiguous buffer (reshape!)
    #pragma unroll
    for (int i = 0; i < 4; ++i) hv[i] += abuf[i*N_ + j] * xv;
  }
  float mpxv = mpx[(size_t)b*D_ + d];
  #pragma unroll
  for (int i = 0; i < 4; ++i) hv[i] += mpxv;
  float s1 = bsum512(hv[0]+hv[1]+hv[2]+hv[3], red);
  float s2 = bsum512(hv[0]*hv[0]+hv[1]*hv[1]+hv[2]*hv[2]+hv[3]*hv[3], red);
  float mu = s1 * (1.f/2048.f);
  float var = s2 * (1.f/2048.f) - mu*mu;
  float rs = 1.f / sqrtf(var + 1e-5f);
  #pragma unroll
  for (int i = 0; i < 4; ++i) {
    int idx = i*D_ + d;
    float v = g2[idx] * ((hv[i]-mu)*rs) + bln2[idx];
    Hh2[(size_t)b*2048 + idx] = v;
    Hh2bf[(size_t)b*2048 + idx] = f2bf(v);
  }
}

// K6: MFMA bf16 fc2 GEMM  [4096,2048] @ [2048,512] + bias -> pred0
// BM=64, BN=128, BK=64; 4 waves 2x2; grid (64,4)=256 blocks.
__global__ __launch_bounds__(256) void k6_fc2(
    const u16* __restrict__ Hh2bf, const u16* __restrict__ fwT,
    const float* __restrict__ fb, float* __restrict__ pred0) {
  __shared__ u16 As[64*72];      // [row][k], stride 72 bf16
  __shared__ u16 Bs[128*72];     // [col][k]
  int tid = threadIdx.x;
  int row0 = blockIdx.x * 64, col0 = blockIdx.y * 128;
  int wid = tid >> 6, lane = tid & 63;
  int wm = wid >> 1, wn = wid & 1;
  int lr = lane & 15, lk = lane >> 4;
  f32x4 acc[2][4] = {};
  bf16x8 raa[2], rbb[4];
  #pragma unroll
  for (int p = 0; p < 2; ++p) {
    int idx = p*256 + tid;
    raa[p] = *(const bf16x8*)&Hh2bf[(size_t)(row0 + (idx>>3))*2048 + ((idx&7)<<3)];
  }
  #pragma unroll
  for (int p = 0; p < 4; ++p) {
    int idx = p*256 + tid;
    rbb[p] = *(const bf16x8*)&fwT[(size_t)(col0 + (idx>>3))*2048 + ((idx&7)<<3)];
  }
  for (int k0 = 0; k0 < 2048; k0 += 64) {
    __syncthreads();
    #pragma unroll
    for (int p = 0; p < 2; ++p) {
      int idx = p*256 + tid;
      *(bf16x8*)&As[(idx>>3)*72 + ((idx&7)<<3)] = raa[p];
    }
    #pragma unroll
    for (int p = 0; p < 4; ++p) {
      int idx = p*256 + tid;
      *(bf16x8*)&Bs[(idx>>3)*72 + ((idx&7)<<3)] = rbb[p];
    }
    __syncthreads();
    if (k0 + 64 < 2048) {
      #pragma unroll
      for (int p = 0; p < 2; ++p) {
        int idx = p*256 + tid;
        raa[p] = *(const bf16x8*)&Hh2bf[(size_t)(row0 + (idx>>3))*2048 + k0 + 64 + ((idx&7)<<3)];
      }
      #pragma unroll
      for (int p = 0; p < 4; ++p) {
        int idx = p*256 + tid;
        rbb[p] = *(const bf16x8*)&fwT[(size_t)(col0 + (idx>>3))*2048 + k0 + 64 + ((idx&7)<<3)];
      }
    }
    #pragma unroll
    for (int kk = 0; kk < 2; ++kk) {
      bf16x8 a[2];
      #pragma unroll
      for (int mf = 0; mf < 2; ++mf)
        a[mf] = *(const bf16x8*)&As[(wm*32 + mf*16 + lr)*72 + kk*32 + lk*8];
      #pragma unroll
      for (int nf = 0; nf < 4; ++nf) {
        bf16x8 bfr = *(const bf16x8*)&Bs[(wn*64 + nf*16 + lr)*72 + kk*32 + lk*8];
        #pragma unroll
        for (int mf = 0; mf < 2; ++mf)
          acc[mf][nf] = __builtin_amdgcn_mfma_f32_16x16x32_bf16(a[mf], bfr, acc[mf][nf], 0, 0, 0);
      }
    }
  }
  #pragma unroll
  for (int mf = 0; mf < 2; ++mf)
    #pragma unroll
    for (int nf = 0; nf < 4; ++nf)
      #pragma unroll
      for (int r = 0; r < 4; ++r) {
        int m = row0 + wm*32 + mf*16 + lk*4 + r;
        int j = col0 + wn*64 + nf*16 + lr;
        pred0[(size_t)m*D_ + j] = acc[mf][nf][r] + fb[j];
      }
}

// K7: LN3, + head-mean of Hh2, LN4 -> out
__global__ __launch_bounds__(512) void k7_final(
    const float* __restrict__ pred0, const float* __restrict__ Hh2,
    const float* __restrict__ g3, const float* __restrict__ b3,
    const float* __restrict__ g4, const float* __restrict__ b4,
    float* __restrict__ out) {
  __shared__ float red[8];
  int b = blockIdx.x, d = threadIdx.x;
  float p = pred0[(size_t)b*D_ + d];
  float s1 = bsum512(p, red);
  float s2 = bsum512(p*p, red);
  float mu = s1*(1.f/D_);
  float var = s2*(1.f/D_) - mu*mu;
  float p3 = g3[d]*((p-mu)/sqrtf(var+1e-5f)) + b3[d];
  const float* hb = Hh2 + (size_t)b*2048;
  float hm = 0.25f*(hb[d] + hb[512+d] + hb[1024+d] + hb[1536+d]);
  float q = p3 + hm;
  s1 = bsum512(q, red);
  s2 = bsum512(q*q, red);
  mu = s1*(1.f/D_);
  var = s2*(1.f/D_) - mu*mu;
  out[(size_t)b*D_ + d] = g4[d]*((q-mu)/sqrtf(var+1e-5f)) + b4[d];
}

extern "C" void kernel_launch(void* const* d_in, const int* in_sizes, int n_in,
                              void* d_out, int out_size, void* d_ws, size_t ws_size,
                              hipStream_t stream) {
  const float* x      = (const float*)d_in[0];
  const unsigned char* amask = (const unsigned char*)d_in[1];
  const int*   order  = (const int*)d_in[2];
  const float* ndocs  = (const float*)d_in[3];
  const float* dw     = (const float*)d_in[4];
  const float* pe     = (const float*)d_in[6];
  const float* w1     = (const float*)d_in[7];
  const float* b1     = (const float*)d_in[8];
  const float* w2     = (const float*)d_in[9];
  const float* b2     = (const float*)d_in[10];
  const float* fw     = (const float*)d_in[11];
  const float* fb     = (const float*)d_in[12];
  const float* g1     = (const float*)d_in[13];
  const float* bln1   = (const float*)d_in[14];
  const float* g2     = (const float*)d_in[15];
  const float* bln2   = (const float*)d_in[16];
  const float* g3     = (const float*)d_in[17];
  const float* b3     = (const float*)d_in[18];
  const float* g4     = (const float*)d_in[19];
  const float* b4     = (const float*)d_in[20];
  float* out = (float*)d_out;

  char* ws = (char*)d_ws;
  size_t off = 0;
  u16*   x1bf   = (u16*)(ws + off);   off += (size_t)M_*D_*2;        // 125.8 MB
  float* mp     = (float*)(ws + off); off += (size_t)B_*D_*4;        // 8.4 MB (dead after k2 -> pred0 aliases)
  float* pred0  = mp;
  float* mpx    = (float*)(ws + off); off += (size_t)B_*D_*4;
  float* mpW    = (float*)(ws + off); off += (size_t)B_*D_*4;
  float* peW    = (float*)(ws + off); off += (size_t)PE_ROWS*D_*4;
  float* cosb   = (float*)(ws + off); off += (size_t)M_*4;
  float* Z      = (float*)(ws + off); off += (size_t)M_*4*4;         // 2.0 MB
  float* Hh2    = (float*)(ws + off); off += (size_t)B_*2048*4;      // 33.6 MB
  u16*   Hh2bf  = (u16*)(ws + off);   off += (size_t)B_*2048*2;      // 16.8 MB
  u16*   w1T    = (u16*)(ws + off);   off += (size_t)D_*D_*2;        // 0.5 MB
  u16*   fwT    = (u16*)(ws + off);   off += (size_t)D_*2048*2;      // 2.1 MB
  (void)ws_size; (void)in_sizes; (void)n_in; (void)out_size;

  k_cvtw1<<<D_, 512, 0, stream>>>(w1, w1T);
  k_cvtfw<<<D_, 512, 0, stream>>>(fw, fwT);
  k_pew<<<PE_ROWS, 512, 0, stream>>>(pe, w1, peW);
  k1_prep<<<B_, 512, 0, stream>>>(x, order, ndocs, dw, pe, g1, bln1,
                                  x1bf, mp, mpx, cosb);
  k2_mpw<<<B_/8, 512, 0, stream>>>(mp, w1, b1, mpW);
  k4_fc1<<<M_/128, 512, 0, stream>>>(x1bf, w1T, w1, w2, order, cosb,
                                     mpW, peW, Z);
  k5_attn<<<B_, 512, 0, stream>>>(Z, b2, amask, x1bf, mpx, g2, bln2, Hh2, Hh2bf);
  k6_fc2<<<dim3(B_/64, 4), 256, 0, stream>>>(Hh2bf, fwT, fb, pred0);
  k7_final<<<B_, 512, 0, stream>>>(pred0, Hh2, g3, b3, g4, b4, out);
}

// Round 4
// 413.853 us; speedup vs baseline: 6.5631x; 1.2243x over previous
//
#include <hip/hip_runtime.h>
#include <hip/hip_bf16.h>

#define B_ 4096
#define N_ 30
#define D_ 512
#define H_ 4
#define M_ (B_*N_)      // 122880 tokens
#define PE_ROWS 31

typedef unsigned short u16;
typedef __attribute__((ext_vector_type(8))) short bf16x8;
typedef __attribute__((ext_vector_type(4))) float f32x4;

__device__ __forceinline__ float bf2f(u16 s) { return __uint_as_float(((unsigned)s) << 16); }
__device__ __forceinline__ u16 f2bf(float f) {
  __hip_bfloat16 h = __float2bfloat16(f);
  return *reinterpret_cast<u16*>(&h);
}

// fast tanh: 1 - 2/(exp(2x)+1); exp->v_exp_f32, rcp->v_rcp_f32 (~1e-7 rel err)
__device__ __forceinline__ float ftanh(float x) {
  float e = __expf(2.f * x);
  return 1.f - 2.f * __builtin_amdgcn_rcpf(e + 1.f);
}

// full-wave (64-lane) sum
__device__ __forceinline__ float wsum(float v) {
  #pragma unroll
  for (int m = 32; m >= 1; m >>= 1) v += __shfl_xor(v, m);
  return v;
}

// block-wide sum over 512 threads (8 waves of 64)
__device__ __forceinline__ float bsum512(float v, float* red) {
  int lane = threadIdx.x & 63;
  int w = threadIdx.x >> 6;
  #pragma unroll
  for (int m = 32; m >= 1; m >>= 1) v += __shfl_xor(v, m);
  if (lane == 0) red[w] = v;
  __syncthreads();
  if (threadIdx.x < 64) {
    float t = (lane < 8) ? red[lane] : 0.0f;
    #pragma unroll
    for (int m = 4; m >= 1; m >>= 1) t += __shfl_xor(t, m);
    if (lane == 0) red[0] = t;
  }
  __syncthreads();
  float r = red[0];
  __syncthreads();
  return r;
}

// K1: wave-per-token. Each of 8 waves owns tokens n = wid+8t (t<4); a token's
// 512-elem row lives as 8 floats/lane. All row reductions are intra-wave
// shfl_xor. Single __syncthreads for the cross-wave mp/mpx pool reduce.
__global__ __launch_bounds__(512) void k1_prep(
    const float* __restrict__ x, const int* __restrict__ order,
    const float* __restrict__ ndocs, const float* __restrict__ dw,
    const float* __restrict__ pe, const float* __restrict__ g1,
    const float* __restrict__ bln1,
    u16* __restrict__ x1bf, float* __restrict__ mp, float* __restrict__ mpx,
    float* __restrict__ cosb) {
  __shared__ float lds_mp[8*512];
  __shared__ float lds_mpx[8*512];
  __shared__ float xps[32];
  int b = blockIdx.x;
  int tid = threadIdx.x;
  int wid = tid >> 6, lane = tid & 63;
  int d0 = lane * 8;
  float g[8], bl[8];
  *(float4*)&g[0]  = *(const float4*)&g1[d0];
  *(float4*)&g[4]  = *(const float4*)&g1[d0+4];
  *(float4*)&bl[0] = *(const float4*)&bln1[d0];
  *(float4*)&bl[4] = *(const float4*)&bln1[d0+4];
  float xp_reg[4][8];
  float accmp[8] = {0,0,0,0,0,0,0,0}, accmpx[8] = {0,0,0,0,0,0,0,0};
  #pragma unroll
  for (int t = 0; t < 4; ++t) {
    int n = wid + 8*t;
    if (n < N_) {
      int tok = b*N_ + n;
      float v[8];
      *(float4*)&v[0] = *(const float4*)&x[(size_t)tok*D_ + d0];
      *(float4*)&v[4] = *(const float4*)&x[(size_t)tok*D_ + d0 + 4];
      float ss = 0.f;
      #pragma unroll
      for (int i = 0; i < 8; ++i) ss += v[i]*v[i];
      ss = wsum(ss);
      float inv = 1.f / fmaxf(sqrtf(ss), 1e-8f);
      float mu = 0.f;
      #pragma unroll
      for (int i = 0; i < 8; ++i) { v[i] *= inv; mu += v[i]; }
      mu = wsum(mu) * (1.f/D_);
      float m2 = ss*inv*inv*(1.f/D_);   // mean(xn^2), exact
      float rs = 1.f / sqrtf(m2 - mu*mu + 1e-5f);
      int o = order[tok];
      float p8[8];
      *(float4*)&p8[0] = *(const float4*)&pe[(size_t)o*D_ + d0];
      *(float4*)&p8[4] = *(const float4*)&pe[(size_t)o*D_ + d0 + 4];
      float wv = dw[tok];
      float sq = 0.f;
      bf16x8 xb;
      #pragma unroll
      for (int i = 0; i < 8; ++i) {
        float x1v = g[i]*((v[i]-mu)*rs) + bl[i];
        xb[i] = (short)f2bf(x1v);
        float xpv = x1v + p8[i];
        xp_reg[t][i] = xpv;
        accmp[i]  += wv*xpv;
        accmpx[i] += wv*x1v;
        sq += xpv*xpv;
      }
      *(bf16x8*)&x1bf[(size_t)tok*D_ + d0] = xb;
      sq = wsum(sq);
      if (lane == 0) xps[n] = sq;
    }
  }
  #pragma unroll
  for (int i = 0; i < 8; i += 4) {
    *(float4*)&lds_mp[wid*512 + d0 + i]  = *(float4*)&accmp[i];
    *(float4*)&lds_mpx[wid*512 + d0 + i] = *(float4*)&accmpx[i];
  }
  __syncthreads();
  float invnd = 1.f / ndocs[b];
  float mpv[8] = {0,0,0,0,0,0,0,0}, mpxv[8] = {0,0,0,0,0,0,0,0};
  #pragma unroll
  for (int w = 0; w < 8; ++w) {
    #pragma unroll
    for (int i = 0; i < 8; i += 4) {
      float4 a = *(float4*)&lds_mp[w*512 + d0 + i];
      mpv[i+0] += a.x; mpv[i+1] += a.y; mpv[i+2] += a.z; mpv[i+3] += a.w;
      float4 c = *(float4*)&lds_mpx[w*512 + d0 + i];
      mpxv[i+0] += c.x; mpxv[i+1] += c.y; mpxv[i+2] += c.z; mpxv[i+3] += c.w;
    }
  }
  #pragma unroll
  for (int i = 0; i < 8; ++i) { mpv[i] *= invnd; mpxv[i] *= invnd; }
  if (wid == 0) {
    #pragma unroll
    for (int i = 0; i < 8; i += 4)
      *(float4*)&mp[(size_t)b*D_ + d0 + i] = *(float4*)&mpv[i];
  }
  if (wid == 1) {
    #pragma unroll
    for (int i = 0; i < 8; i += 4)
      *(float4*)&mpx[(size_t)b*D_ + d0 + i] = *(float4*)&mpxv[i];
  }
  float mn = 0.f;
  #pragma unroll
  for (int i = 0; i < 8; ++i) mn += mpv[i]*mpv[i];
  float mpn = sqrtf(wsum(mn));
  #pragma unroll
  for (int t = 0; t < 4; ++t) {
    int n = wid + 8*t;
    if (n < N_) {
      float dot = 0.f;
      #pragma unroll
      for (int i = 0; i < 8; ++i) dot += mpv[i]*xp_reg[t][i];
      dot = wsum(dot);
      if (lane == 0)
        cosb[b*N_ + n] = dot / fmaxf(mpn * sqrtf(xps[n]), 1e-8f);
    }
  }
}

// peW[p][j] = pos_emb[p] @ W_top   (31 x 512)
__global__ __launch_bounds__(512) void k_pew(
    const float* __restrict__ pe, const float* __restrict__ w1,
    float* __restrict__ peW) {
  int p = blockIdx.x, j = threadIdx.x;
  float acc = 0.f;
  for (int dd = 0; dd < D_; ++dd) acc += pe[p*D_ + dd] * w1[(size_t)dd*D_ + j];
  peW[p*D_ + j] = acc;
}

// mpW[b][j] = mp[b] @ W_mid + fc1_b1[j]   (8 batches per block)
__global__ __launch_bounds__(512) void k2_mpw(
    const float* __restrict__ mp, const float* __restrict__ w1,
    const float* __restrict__ b1, float* __restrict__ mpW) {
  __shared__ float mps[8][D_];
  int j = threadIdx.x;
  int b0 = blockIdx.x * 8;
  #pragma unroll
  for (int r = 0; r < 8; ++r) mps[r][j] = mp[(size_t)(b0+r)*D_ + j];
  __syncthreads();
  float bv = b1[j];
  float acc[8] = {bv,bv,bv,bv,bv,bv,bv,bv};
  for (int dd = 0; dd < D_; ++dd) {
    float wv = w1[(size_t)(D_+dd)*D_ + j];
    #pragma unroll
    for (int r = 0; r < 8; ++r) acc[r] += mps[r][dd] * wv;
  }
  #pragma unroll
  for (int r = 0; r < 8; ++r) mpW[(size_t)(b0+r)*D_ + j] = acc[r];
}

// Tiled transpose+convert: out[j][k] = bf16(in[k][j]). 64x64 tiles, 256 thr.
// Coalesced float4 loads, LDS tile (pad 65), 8B u16x4 stores.
__global__ __launch_bounds__(256) void k_tcvt(
    const float* __restrict__ in, u16* __restrict__ out, int Kdim, int Jdim) {
  __shared__ float tile[64][65];
  int k0 = blockIdx.x * 64, j0 = blockIdx.y * 64;
  int t = threadIdx.x;
  int tr = t >> 4, tc4 = (t & 15) * 4;
  #pragma unroll
  for (int i = 0; i < 4; ++i) {
    int k = k0 + tr + i*16;
    float4 v = *(const float4*)&in[(size_t)k*Jdim + j0 + tc4];
    tile[tr + i*16][tc4+0] = v.x;
    tile[tr + i*16][tc4+1] = v.y;
    tile[tr + i*16][tc4+2] = v.z;
    tile[tr + i*16][tc4+3] = v.w;
  }
  __syncthreads();
  #pragma unroll
  for (int i = 0; i < 4; ++i) {
    int j = tr + i*16;
    uint2 u;
    u.x = (unsigned)f2bf(tile[tc4+0][j]) | ((unsigned)f2bf(tile[tc4+1][j]) << 16);
    u.y = (unsigned)f2bf(tile[tc4+2][j]) | ((unsigned)f2bf(tile[tc4+3][j]) << 16);
    *(uint2*)&out[(size_t)(j0+j)*Kdim + k0 + tc4] = u;
  }
}

// K4 v3: MFMA bf16 GEMM  pre = x1 @ W_top, with the per-row/col additive terms
// (mpW + peW + cos*w1_last) folded into the ACCUMULATOR INIT (loads issue at
// kernel start, latency hidden under staging/MFMA). Epilogue = fast-tanh +
// w2-dot from registers + shfl reduce. LDS 51200B (zred aliased) -> 3 blk/CU.
__global__ __launch_bounds__(512) void k4_fc1(
    const u16* __restrict__ x1bf, const u16* __restrict__ w1T,
    const float* __restrict__ w1, const float* __restrict__ w2,
    const int* __restrict__ order, const float* __restrict__ cosb,
    const float* __restrict__ mpW, const float* __restrict__ peW,
    float* __restrict__ Z) {
  __shared__ __align__(16) char smem[(128*40 + 512*40)*2];   // 51200 B
  u16* As = (u16*)smem;                  // [128][40]
  u16* Bs = (u16*)smem + 128*40;         // [512][40]
  float* zred = (float*)smem;            // epilogue alias: [4][128][4] = 8KB
  int tid = threadIdx.x;
  int row0 = blockIdx.x * 128;
  int wid = tid >> 6, lane = tid & 63;
  int wm = wid >> 2, wn = wid & 3;
  int lr = lane & 15, lk = lane >> 4;
  int sra = tid >> 2, ska = (tid & 3) << 3;
  // per-lane w2 rows and cos-coefficient row (registers, no LDS)
  float w2r[8][4], wl[8];
  #pragma unroll
  for (int nf = 0; nf < 8; ++nf) {
    int jl = wn*128 + nf*16 + lr;
    *(float4*)w2r[nf] = *(const float4*)&w2[jl*4];
    wl[nf] = w1[(size_t)1024*D_ + jl];
  }
  // accumulator init = mpW[bidx][jl] + peW[o][jl] + cs*wl[jl]
  f32x4 acc[4][8];
  #pragma unroll
  for (int mf = 0; mf < 4; ++mf) {
    #pragma unroll
    for (int r = 0; r < 4; ++r) {
      int m = row0 + wm*64 + mf*16 + lk*4 + r;
      int bidx = m / N_;
      int o = order[m];
      float cs = cosb[m];
      #pragma unroll
      for (int nf = 0; nf < 8; ++nf) {
        int jl = wn*128 + nf*16 + lr;
        acc[mf][nf][r] = mpW[(size_t)bidx*D_ + jl] + peW[o*D_ + jl] + cs*wl[nf];
      }
    }
  }
  bf16x8 ra, rb[4];
  ra = *(const bf16x8*)&x1bf[(size_t)(row0 + sra)*D_ + ska];
  #pragma unroll
  for (int p = 0; p < 4; ++p) {
    int idx = p*512 + tid;
    int c = idx >> 2, kc = (idx & 3) << 3;
    rb[p] = *(const bf16x8*)&w1T[(size_t)c*D_ + kc];
  }
  for (int k0 = 0; k0 < D_; k0 += 32) {
    __syncthreads();
    *(bf16x8*)&As[sra*40 + ska] = ra;
    #pragma unroll
    for (int p = 0; p < 4; ++p) {
      int idx = p*512 + tid;
      int c = idx >> 2, kc = (idx & 3) << 3;
      *(bf16x8*)&Bs[c*40 + kc] = rb[p];
    }
    __syncthreads();
    if (k0 + 32 < D_) {       // prefetch next tile while MFMAs run
      ra = *(const bf16x8*)&x1bf[(size_t)(row0 + sra)*D_ + k0 + 32 + ska];
      #pragma unroll
      for (int p = 0; p < 4; ++p) {
        int idx = p*512 + tid;
        int c = idx >> 2, kc = (idx & 3) << 3;
        rb[p] = *(const bf16x8*)&w1T[(size_t)c*D_ + k0 + 32 + kc];
      }
    }
    bf16x8 a[4];
    #pragma unroll
    for (int mf = 0; mf < 4; ++mf)
      a[mf] = *(const bf16x8*)&As[(wm*64 + mf*16 + lr)*40 + lk*8];
    #pragma unroll
    for (int nf = 0; nf < 8; ++nf) {
      bf16x8 bfr = *(const bf16x8*)&Bs[(wn*128 + nf*16 + lr)*40 + lk*8];
      #pragma unroll
      for (int mf = 0; mf < 4; ++mf)
        acc[mf][nf] = __builtin_amdgcn_mfma_f32_16x16x32_bf16(a[mf], bfr, acc[mf][nf], 0, 0, 0);
    }
  }
  __syncthreads();   // all LDS frag reads done -> safe to alias zred
  #pragma unroll
  for (int mf = 0; mf < 4; ++mf) {
    #pragma unroll
    for (int r = 0; r < 4; ++r) {
      int rowt = wm*64 + mf*16 + lk*4 + r;
      float z0=0.f, z1=0.f, z2=0.f, z3=0.f;
      #pragma unroll
      for (int nf = 0; nf < 8; ++nf) {
        float t = ftanh(acc[mf][nf][r]);
        z0 += t * w2r[nf][0]; z1 += t * w2r[nf][1];
        z2 += t * w2r[nf][2]; z3 += t * w2r[nf][3];
      }
      #pragma unroll
      for (int msk = 1; msk <= 8; msk <<= 1) {
        z0 += __shfl_xor(z0, msk); z1 += __shfl_xor(z1, msk);
        z2 += __shfl_xor(z2, msk); z3 += __shfl_xor(z3, msk);
      }
      if (lr == 0)
        *(float4*)&zred[(wn*128 + rowt)*4] = make_float4(z0, z1, z2, z3);
    }
  }
  __syncthreads();
  if (tid < 128) {
    float4 s0 = *(float4*)&zred[(0*128 + tid)*4];
    float4 s1 = *(float4*)&zred[(1*128 + tid)*4];
    float4 s2 = *(float4*)&zred[(2*128 + tid)*4];
    float4 s3 = *(float4*)&zred[(3*128 + tid)*4];
    float4 s;
    s.x = s0.x+s1.x+s2.x+s3.x; s.y = s0.y+s1.y+s2.y+s3.y;
    s.z = s0.z+s1.z+s2.z+s3.z; s.w = s0.w+s1.w+s2.w+s3.w;
    *(float4*)&Z[(size_t)(row0 + tid)*4] = s;
  }
}

// K5: per-batch. Z -> mask/softmax, reshape-faithful attention pool over x1,
// +mpx tile, LN2 -> Hh2 [B,2048] (f32 + bf16 copy for fc2)
__global__ __launch_bounds__(512) void k5_attn(
    const float* __restrict__ Z, const float* __restrict__ b2,
    const unsigned char* __restrict__ amask, const u16* __restrict__ x1bf,
    const float* __restrict__ mpx, const float* __restrict__ g2,
    const float* __restrict__ bln2, float* __restrict__ Hh2,
    u16* __restrict__ Hh2bf) {
  __shared__ float abuf[N_*H_];   // [n][h] flat; reused z -> A
  __shared__ float red[8];
  int b = blockIdx.x;
  int tid = threadIdx.x;
  if (tid < N_*H_) {
    int n = tid >> 2, h = tid & 3;
    float z = b2[h] + Z[(size_t)(b*N_ + n)*4 + h];
    if (amask[b*N_ + n]) z = -INFINITY;
    abuf[n*4 + h] = z;
  }
  __syncthreads();
  if (tid < H_) {   // per-head softmax over n
    int h = tid;
    float mx = -INFINITY;
    for (int n = 0; n < N_; ++n) mx = fmaxf(mx, abuf[n*4+h]);
    float s = 0.f;
    for (int n = 0; n < N_; ++n) s += __expf(abuf[n*4+h] - mx);
    float inv = 1.f / s;
    for (int n = 0; n < N_; ++n) abuf[n*4+h] = __expf(abuf[n*4+h] - mx) * inv;
  }
  __syncthreads();
  int d = tid;
  float hv[4] = {0,0,0,0};
  for (int j = 0; j < N_; ++j) {
    float xv = bf2f(x1bf[(size_t)(b*N_ + j)*D_ + d]);
    // A_h[i][j] = A.flat[i*30+j] on the [n][h]-contiguous buffer (reshape!)
    #pragma unroll
    for (int i = 0; i < 4; ++i) hv[i] += abuf[i*N_ + j] * xv;
  }
  float mpxv = mpx[(size_t)b*D_ + d];
  #pragma unroll
  for (int i = 0; i < 4; ++i) hv[i] += mpxv;
  float s1 = bsum512(hv[0]+hv[1]+hv[2]+hv[3], red);
  float s2 = bsum512(hv[0]*hv[0]+hv[1]*hv[1]+hv[2]*hv[2]+hv[3]*hv[3], red);
  float mu = s1 * (1.f/2048.f);
  float var = s2 * (1.f/2048.f) - mu*mu;
  float rs = 1.f / sqrtf(var + 1e-5f);
  #pragma unroll
  for (int i = 0; i < 4; ++i) {
    int idx = i*D_ + d;
    float v = g2[idx] * ((hv[i]-mu)*rs) + bln2[idx];
    Hh2[(size_t)b*2048 + idx] = v;
    Hh2bf[(size_t)b*2048 + idx] = f2bf(v);
  }
}

// K6: MFMA bf16 fc2 GEMM  [4096,2048] @ [2048,512] + bias -> pred0
__global__ __launch_bounds__(256) void k6_fc2(
    const u16* __restrict__ Hh2bf, const u16* __restrict__ fwT,
    const float* __restrict__ fb, float* __restrict__ pred0) {
  __shared__ u16 As[64*72];      // [row][k], stride 72 bf16
  __shared__ u16 Bs[128*72];     // [col][k]
  int tid = threadIdx.x;
  int row0 = blockIdx.x * 64, col0 = blockIdx.y * 128;
  int wid = tid >> 6, lane = tid & 63;
  int wm = wid >> 1, wn = wid & 1;
  int lr = lane & 15, lk = lane >> 4;
  f32x4 acc[2][4] = {};
  bf16x8 raa[2], rbb[4];
  #pragma unroll
  for (int p = 0; p < 2; ++p) {
    int idx = p*256 + tid;
    raa[p] = *(const bf16x8*)&Hh2bf[(size_t)(row0 + (idx>>3))*2048 + ((idx&7)<<3)];
  }
  #pragma unroll
  for (int p = 0; p < 4; ++p) {
    int idx = p*256 + tid;
    rbb[p] = *(const bf16x8*)&fwT[(size_t)(col0 + (idx>>3))*2048 + ((idx&7)<<3)];
  }
  for (int k0 = 0; k0 < 2048; k0 += 64) {
    __syncthreads();
    #pragma unroll
    for (int p = 0; p < 2; ++p) {
      int idx = p*256 + tid;
      *(bf16x8*)&As[(idx>>3)*72 + ((idx&7)<<3)] = raa[p];
    }
    #pragma unroll
    for (int p = 0; p < 4; ++p) {
      int idx = p*256 + tid;
      *(bf16x8*)&Bs[(idx>>3)*72 + ((idx&7)<<3)] = rbb[p];
    }
    __syncthreads();
    if (k0 + 64 < 2048) {
      #pragma unroll
      for (int p = 0; p < 2; ++p) {
        int idx = p*256 + tid;
        raa[p] = *(const bf16x8*)&Hh2bf[(size_t)(row0 + (idx>>3))*2048 + k0 + 64 + ((idx&7)<<3)];
      }
      #pragma unroll
      for (int p = 0; p < 4; ++p) {
        int idx = p*256 + tid;
        rbb[p] = *(const bf16x8*)&fwT[(size_t)(col0 + (idx>>3))*2048 + k0 + 64 + ((idx&7)<<3)];
      }
    }
    #pragma unroll
    for (int kk = 0; kk < 2; ++kk) {
      bf16x8 a[2];
      #pragma unroll
      for (int mf = 0; mf < 2; ++mf)
        a[mf] = *(const bf16x8*)&As[(wm*32 + mf*16 + lr)*72 + kk*32 + lk*8];
      #pragma unroll
      for (int nf = 0; nf < 4; ++nf) {
        bf16x8 bfr = *(const bf16x8*)&Bs[(wn*64 + nf*16 + lr)*72 + kk*32 + lk*8];
        #pragma unroll
        for (int mf = 0; mf < 2; ++mf)
          acc[mf][nf] = __builtin_amdgcn_mfma_f32_16x16x32_bf16(a[mf], bfr, acc[mf][nf], 0, 0, 0);
      }
    }
  }
  #pragma unroll
  for (int mf = 0; mf < 2; ++mf)
    #pragma unroll
    for (int nf = 0; nf < 4; ++nf)
      #pragma unroll
      for (int r = 0; r < 4; ++r) {
        int m = row0 + wm*32 + mf*16 + lk*4 + r;
        int j = col0 + wn*64 + nf*16 + lr;
        pred0[(size_t)m*D_ + j] = acc[mf][nf][r] + fb[j];
      }
}

// K7: LN3, + head-mean of Hh2, LN4 -> out
__global__ __launch_bounds__(512) void k7_final(
    const float* __restrict__ pred0, const float* __restrict__ Hh2,
    const float* __restrict__ g3, const float* __restrict__ b3,
    const float* __restrict__ g4, const float* __restrict__ b4,
    float* __restrict__ out) {
  __shared__ float red[8];
  int b = blockIdx.x, d = threadIdx.x;
  float p = pred0[(size_t)b*D_ + d];
  float s1 = bsum512(p, red);
  float s2 = bsum512(p*p, red);
  float mu = s1*(1.f/D_);
  float var = s2*(1.f/D_) - mu*mu;
  float p3 = g3[d]*((p-mu)/sqrtf(var+1e-5f)) + b3[d];
  const float* hb = Hh2 + (size_t)b*2048;
  float hm = 0.25f*(hb[d] + hb[512+d] + hb[1024+d] + hb[1536+d]);
  float q = p3 + hm;
  s1 = bsum512(q, red);
  s2 = bsum512(q*q, red);
  mu = s1*(1.f/D_);
  var = s2*(1.f/D_) - mu*mu;
  out[(size_t)b*D_ + d] = g4[d]*((q-mu)/sqrtf(var+1e-5f)) + b4[d];
}

extern "C" void kernel_launch(void* const* d_in, const int* in_sizes, int n_in,
                              void* d_out, int out_size, void* d_ws, size_t ws_size,
                              hipStream_t stream) {
  const float* x      = (const float*)d_in[0];
  const unsigned char* amask = (const unsigned char*)d_in[1];
  const int*   order  = (const int*)d_in[2];
  const float* ndocs  = (const float*)d_in[3];
  const float* dw     = (const float*)d_in[4];
  const float* pe     = (const float*)d_in[6];
  const float* w1     = (const float*)d_in[7];
  const float* b1     = (const float*)d_in[8];
  const float* w2     = (const float*)d_in[9];
  const float* b2     = (const float*)d_in[10];
  const float* fw     = (const float*)d_in[11];
  const float* fb     = (const float*)d_in[12];
  const float* g1     = (const float*)d_in[13];
  const float* bln1   = (const float*)d_in[14];
  const float* g2     = (const float*)d_in[15];
  const float* bln2   = (const float*)d_in[16];
  const float* g3     = (const float*)d_in[17];
  const float* b3     = (const float*)d_in[18];
  const float* g4     = (const float*)d_in[19];
  const float* b4     = (const float*)d_in[20];
  float* out = (float*)d_out;

  char* ws = (char*)d_ws;
  size_t off = 0;
  u16*   x1bf   = (u16*)(ws + off);   off += (size_t)M_*D_*2;        // 125.8 MB
  float* mp     = (float*)(ws + off); off += (size_t)B_*D_*4;        // dead after k2 -> pred0 aliases
  float* pred0  = mp;
  float* mpx    = (float*)(ws + off); off += (size_t)B_*D_*4;
  float* mpW    = (float*)(ws + off); off += (size_t)B_*D_*4;
  float* peW    = (float*)(ws + off); off += (size_t)PE_ROWS*D_*4;
  float* cosb   = (float*)(ws + off); off += (size_t)M_*4;
  float* Z      = (float*)(ws + off); off += (size_t)M_*4*4;         // 2.0 MB
  float* Hh2    = (float*)(ws + off); off += (size_t)B_*2048*4;      // 33.6 MB
  u16*   Hh2bf  = (u16*)(ws + off);   off += (size_t)B_*2048*2;      // 16.8 MB
  u16*   w1T    = (u16*)(ws + off);   off += (size_t)D_*D_*2;        // 0.5 MB
  u16*   fwT    = (u16*)(ws + off);   off += (size_t)D_*2048*2;      // 2.1 MB
  (void)ws_size; (void)in_sizes; (void)n_in; (void)out_size;

  k_tcvt<<<dim3(8, 8), 256, 0, stream>>>(w1, w1T, 512, 512);      // W_top^T
  k_tcvt<<<dim3(32, 8), 256, 0, stream>>>(fw, fwT, 2048, 512);    // fc2_w^T
  k_pew<<<PE_ROWS, 512, 0, stream>>>(pe, w1, peW);
  k1_prep<<<B_, 512, 0, stream>>>(x, order, ndocs, dw, pe, g1, bln1,
                                  x1bf, mp, mpx, cosb);
  k2_mpw<<<B_/8, 512, 0, stream>>>(mp, w1, b1, mpW);
  k4_fc1<<<M_/128, 512, 0, stream>>>(x1bf, w1T, w1, w2, order, cosb,
                                     mpW, peW, Z);
  k5_attn<<<B_, 512, 0, stream>>>(Z, b2, amask, x1bf, mpx, g2, bln2, Hh2, Hh2bf);
  k6_fc2<<<dim3(B_/64, 4), 256, 0, stream>>>(Hh2bf, fwT, fb, pred0);
  k7_final<<<B_, 512, 0, stream>>>(pred0, Hh2, g3, b3, g4, b4, out);
}